// Round 4
// baseline (370.496 us; speedup 1.0000x reference)
//
#include <hip/hip_runtime.h>
#include <hip/hip_bf16.h>
#include <stdint.h>

typedef unsigned short u16;
typedef unsigned int   u32;
typedef unsigned long long u64;
typedef __bf16 bf16x8 __attribute__((ext_vector_type(8)));
typedef float  f32x4  __attribute__((ext_vector_type(4)));

__device__ __forceinline__ u16 b2u(__bf16 b){ union U{__bf16 b; u16 u;} v; v.b=b; return v.u; }

__device__ __forceinline__ f32x4 MFMA16(bf16x8 a, bf16x8 b, f32x4 c) {
  return __builtin_amdgcn_mfma_f32_16x16x32_bf16(a, b, c, 0, 0, 0);
}

// ---- LDS: two 14336 B weight buffers + 8 x 2304 B wave-private scratch ----
#define LDS_WA   0
#define LDS_WB   14336
#define LDS_SCR  28672
#define SCR_STRIDE 2304
#define LDS_TOTAL 47104   // + harness 32K tax = 79872 -> 2 WG/CU

// weight fragment blocks (2048 B each): layer bases in blocks
#define BL2 140   // L1: 10 kc x 14 nt = 140 blocks
#define BL3 189   // L2: 7 kc x 7 nt = 49
#define BL4 205   // L3: 4 kc x 4 nt = 16
#define NBLOCKS 207   // L4: 2 kc x 1 nt = 2

#define VMCNT0 asm volatile("s_waitcnt vmcnt(0)" ::: "memory")

// ---------------- weight prep: fp32 [N][K] -> bf16 hi/lo B-fragment blocks ----
// 16x16x32 B-frag: lane l holds col n = nt*16 + (l&15), k = kc*32 + (l>>4)*8 + j
// block = 2048 B = [hi: 64 lanes x 16 B][lo: 64 lanes x 16 B]
__global__ __launch_bounds__(64) void prep_kernel(
    const float* __restrict__ W1, const float* __restrict__ W2,
    const float* __restrict__ W3, const float* __restrict__ W4,
    u16* __restrict__ wf)
{
  int b = blockIdx.x, lane = threadIdx.x;
  const float* W; int NT, rel, Nv, Kv;
  if (b < BL2)      { W = W1; NT = 14; rel = b;       Nv = 200; Kv = 300; }
  else if (b < BL3) { W = W2; NT = 7;  rel = b - BL2; Nv = 100; Kv = 200; }
  else if (b < BL4) { W = W3; NT = 4;  rel = b - BL3; Nv = 50;  Kv = 100; }
  else              { W = W4; NT = 1;  rel = b - BL4; Nv = 10;  Kv = 50;  }
  int kc = rel / NT, nt = rel % NT;
  int n  = nt * 16 + (lane & 15);
  int kb = kc * 32 + ((lane >> 4) << 3);
  u16* dst = wf + (size_t)b * 1024;
  #pragma unroll
  for (int j = 0; j < 8; ++j) {
    int k = kb + j;
    float w = (n < Nv && k < Kv) ? W[n * Kv + k] : 0.0f;
    __bf16 h = (__bf16)w;
    __bf16 l = (__bf16)(w - (float)h);
    dst[lane * 8 + j]       = b2u(h);
    dst[512 + lane * 8 + j] = b2u(l);
  }
}

// ---- T14 reg staging (round-2-proven): issue loads early, LDS write late ----
template<int CHUNK>
__device__ __forceinline__ void stage_load(const char* __restrict__ g, float4* r, int tid) {
  constexpr int NS = (CHUNK + 8191) / 8192;
  #pragma unroll
  for (int it = 0; it < NS; ++it) {
    const int off = tid * 16 + it * 8192;
    if ((it + 1) * 8192 <= CHUNK) r[it] = *(const float4*)(g + off);
    else if (off < CHUNK)         r[it] = *(const float4*)(g + off);
  }
}
template<int CHUNK>
__device__ __forceinline__ void stage_write(char* lds, const float4* r, int tid) {
  constexpr int NS = (CHUNK + 8191) / 8192;
  #pragma unroll
  for (int it = 0; it < NS; ++it) {
    const int off = tid * 16 + it * 8192;
    if ((it + 1) * 8192 <= CHUNK) *(float4*)(lds + off) = r[it];
    else if (off < CHUNK)         *(float4*)(lds + off) = r[it];
  }
}

// ---- layer transition (wave-private, plain LDS, stride-72 rows) ----
// scratch: hi plane rows m=0..15 at byte m*72 (k_local*2 within row), lo at +1152
// writer: value(m = q*4+r, k_local = hh*16+col) ; reader: lane gets
// frag[j] = H[m=col][k = q*8+j] as two b64 at col*72 + q*16 (+8)
template<int TIN>
__device__ __forceinline__ void transition(const f32x4* acc,
    const float* __restrict__ bias, int nvalid,
    bf16x8* oh, bf16x8* ol, char* scr, int lane)
{
  const int col = lane & 15, q = lane >> 4;
  float bv[TIN];
  #pragma unroll
  for (int t = 0; t < TIN; ++t) {
    const int n = t * 16 + col;
    bv[t] = (n < nvalid) ? bias[n] : 0.0f;
  }
  constexpr int KC = (TIN + 1) / 2;
  #pragma unroll
  for (int kc = 0; kc < KC; ++kc) {
    #pragma unroll
    for (int hh = 0; hh < 2; ++hh) {
      const int t = 2 * kc + hh;
      #pragma unroll
      for (int r = 0; r < 4; ++r) {
        float v = 0.0f;
        if (t < TIN) v = fmaxf(acc[t][r] + bv[t], 0.0f);
        __bf16 h = (__bf16)v;
        __bf16 l = (__bf16)(v - (float)h);
        const int m = q * 4 + r;
        char* wp = scr + m * 72 + (hh * 16 + col) * 2;
        *(u16*)wp           = b2u(h);
        *(u16*)(wp + 1152)  = b2u(l);
      }
    }
    // wait for this wave's stores, and fence compiler reordering across phases
    asm volatile("s_waitcnt lgkmcnt(0)" ::: "memory");
    const char* rp = scr + col * 72 + q * 16;
    union { u64 u[2]; bf16x8 v; } ph, pl;
    ph.u[0] = *(const u64*)(rp);
    ph.u[1] = *(const u64*)(rp + 8);
    pl.u[0] = *(const u64*)(rp + 1152);
    pl.u[1] = *(const u64*)(rp + 1160);
    oh[kc] = ph.v;
    ol[kc] = pl.v;
  }
}

// ---- generic LDS-weight layer (A-fragments in registers) ----
template<int NT, int NKC>
__device__ __forceinline__ void layerN(char* lds, const char* wl,
    f32x4* acc, const bf16x8* ah, const bf16x8* al, int lane, int tid)
{
  constexpr int CH = NT * 2048;
  #pragma unroll
  for (int s = 0; s < NKC; ++s) {
    float4 sr[(CH + 8191) / 8192];
    if (s + 1 < NKC) stage_load<CH>(wl + (size_t)(s + 1) * CH, sr, tid);
    const char* wb = lds + ((s & 1) ? LDS_WB : LDS_WA);
    #pragma unroll
    for (int nt = 0; nt < NT; ++nt) {
      const char* bp = wb + nt * 2048 + (size_t)lane * 16;
      bf16x8 bh = *(const bf16x8*)bp;
      bf16x8 bl = *(const bf16x8*)(bp + 1024);
      acc[nt] = MFMA16(ah[s], bh, acc[nt]);
      acc[nt] = MFMA16(ah[s], bl, acc[nt]);
      acc[nt] = MFMA16(al[s], bh, acc[nt]);
    }
    if (s + 1 < NKC) { VMCNT0; stage_write<CH>(lds + ((s & 1) ? LDS_WA : LDS_WB), sr, tid); }
    __syncthreads();
  }
}

// ---- quantum epilogue (verified rounds 1-2) ----
struct cpx { float r, i; };
__device__ __forceinline__ void ry_pair(float c, float s, cpx& a, cpx& b) {
  cpx na = { c*a.r - s*b.r, c*a.i - s*b.i };
  cpx nb = { s*a.r + c*b.r, s*a.i + c*b.i };
  a = na; b = nb;
}
__device__ __forceinline__ void rx_pair(float c, float s, cpx& a, cpx& b) {
  cpx na = { c*a.r + s*b.i, c*a.i - s*b.r };
  cpx nb = { s*a.i + c*b.r, -s*a.r + c*b.i };
  a = na; b = nb;
}
__device__ void build_state(const float* p, cpx v[4]) {
  float a1 = 0.5f*p[1], a2 = 0.5f*p[2], a3 = 0.5f*p[3];
  float c2 = cosf(a2), s2 = sinf(a2), c3 = cosf(a3), s3 = sinf(a3);
  v[0] = { c2*c3, 0.f }; v[1] = { c2*s3, 0.f };
  v[2] = { s2*c3, 0.f }; v[3] = { s2*s3, 0.f };
  float c1 = cosf(a1), s1 = sinf(a1);
  rx_pair(c1, s1, v[0], v[1]); rx_pair(c1, s1, v[2], v[3]);
  rx_pair(c1, s1, v[0], v[2]); rx_pair(c1, s1, v[1], v[3]);
  float q1 = 0.5f*p[6], q2 = 0.5f*p[7], q3 = 0.5f*p[8], q4 = 0.5f*p[9];
  float c4 = cosf(q4), s4 = sinf(q4);
  rx_pair(c4, s4, v[1], v[3]);
  float cc = cosf(q3), ss = sinf(q3);
  ry_pair(cc, ss, v[0], v[1]); ry_pair(cc, ss, v[2], v[3]);
  cc = cosf(q2); ss = sinf(q2);
  ry_pair(cc, ss, v[0], v[2]); ry_pair(cc, ss, v[1], v[3]);
  cc = cosf(q1); ss = sinf(q1);
  rx_pair(cc, ss, v[0], v[1]); rx_pair(cc, ss, v[2], v[3]);
  rx_pair(cc, ss, v[0], v[2]); rx_pair(cc, ss, v[1], v[3]);
}

__device__ __forceinline__ bf16x8 cvt8(float4 a, float4 b) {
  bf16x8 r;
  r[0]=(__bf16)a.x; r[1]=(__bf16)a.y; r[2]=(__bf16)a.z; r[3]=(__bf16)a.w;
  r[4]=(__bf16)b.x; r[5]=(__bf16)b.y; r[6]=(__bf16)b.z; r[7]=(__bf16)b.w;
  return r;
}
__device__ __forceinline__ void loadX(const float* xp, int kc, int q,
                                      float4& a, float4& b) {
  int k0 = kc * 32 + q * 8;
  a = (k0     < 300) ? *(const float4*)(xp + k0)     : make_float4(0,0,0,0);
  b = (k0 + 4 < 300) ? *(const float4*)(xp + k0 + 4) : make_float4(0,0,0,0);
}

// ---- fused kernel: 8 waves x 16 rows = 128 rows of [2B,300] per WG ----
__global__ __launch_bounds__(512, 4) void fused_kernel(
    const float* __restrict__ X,
    const float* __restrict__ b1p, const float* __restrict__ b2p,
    const float* __restrict__ b3p, const float* __restrict__ b4p,
    const u16* __restrict__ wf,
    float* __restrict__ out)
{
  __shared__ char lds[LDS_TOTAL] __attribute__((aligned(16)));
  const int tid  = threadIdx.x;
  const int lane = tid & 63;
  const int wid  = tid >> 6;
  const int q    = lane >> 4;
  char* scr = lds + LDS_SCR + wid * SCR_STRIDE;
  const char* wfc = (const char*)wf;
  const long rowbase = (long)blockIdx.x * 128 + wid * 16;
  const float* xp = X + (rowbase + (lane & 15)) * 300;

  // prologue: stage L1 chunk0 (kc0, nts 0-6), load X kc0
  float4 s0[2];
  stage_load<14336>(wfc, s0, tid);
  float4 fxa, fxb;
  loadX(xp, 0, q, fxa, fxb);
  VMCNT0;
  stage_write<14336>(lds + LDS_WA, s0, tid);
  bf16x8 xcur = cvt8(fxa, fxb);
  __syncthreads();

  // ---- L1: 20 half-steps (10 kc x 2 nt-halves); 7 nt x 2 MFMA per step ----
  f32x4 acc1[14] = {};
  #pragma unroll
  for (int s = 0; s < 20; ++s) {
    float4 sr[2];
    if (s < 19) stage_load<14336>(wfc + (size_t)(s + 1) * 14336, sr, tid);
    if (!(s & 1) && s < 18) loadX(xp, (s >> 1) + 1, q, fxa, fxb);
    const char* wb = lds + ((s & 1) ? LDS_WB : LDS_WA);
    f32x4* acch = acc1 + (s & 1) * 7;
    #pragma unroll
    for (int nt = 0; nt < 7; ++nt) {
      const char* bp = wb + nt * 2048 + (size_t)lane * 16;
      bf16x8 bh = *(const bf16x8*)bp;
      bf16x8 bl = *(const bf16x8*)(bp + 1024);
      acch[nt] = MFMA16(xcur, bh, acch[nt]);
      acch[nt] = MFMA16(xcur, bl, acch[nt]);
    }
    if (s < 19) { VMCNT0; stage_write<14336>(lds + ((s & 1) ? LDS_WA : LDS_WB), sr, tid); }
    if ((s & 1) && s < 19) xcur = cvt8(fxa, fxb);
    __syncthreads();
  }

  // ---- L1 -> L2 ----
  float4 s2[2];
  stage_load<14336>(wfc + (size_t)BL2 * 2048, s2, tid);
  bf16x8 h1h[7], h1l[7];
  transition<14>(acc1, b1p, 200, h1h, h1l, scr, lane);
  VMCNT0;
  stage_write<14336>(lds + LDS_WA, s2, tid);
  __syncthreads();

  f32x4 acc2[7] = {};
  layerN<7, 7>(lds, wfc + (size_t)BL2 * 2048, acc2, h1h, h1l, lane, tid);

  // ---- L2 -> L3 ----
  float4 s3[1];
  stage_load<8192>(wfc + (size_t)BL3 * 2048, s3, tid);
  bf16x8 h2h[4], h2l[4];
  transition<7>(acc2, b2p, 100, h2h, h2l, scr, lane);
  VMCNT0;
  stage_write<8192>(lds + LDS_WA, s3, tid);
  __syncthreads();

  f32x4 acc3[4] = {};
  layerN<4, 4>(lds, wfc + (size_t)BL3 * 2048, acc3, h2h, h2l, lane, tid);

  // ---- L3 -> L4 ----
  float4 s4[1];
  stage_load<2048>(wfc + (size_t)BL4 * 2048, s4, tid);
  bf16x8 h3h[2], h3l[2];
  transition<4>(acc3, b3p, 50, h3h, h3l, scr, lane);
  VMCNT0;
  stage_write<2048>(lds + LDS_WA, s4, tid);
  __syncthreads();

  f32x4 acc4[1] = {};
  layerN<1, 2>(lds, wfc + (size_t)BL4 * 2048, acc4, h3h, h3l, lane, tid);

  // ---- epilogue: params via wave-private f32 scratch, quantum math, store ----
  {
    const int col = lane & 15;
    float* sp = (float*)scr;   // [16 rows][16 cols] f32
    #pragma unroll
    for (int r = 0; r < 4; ++r) {
      const int row = q * 4 + r;
      sp[row * 16 + col] = acc4[0][r] + ((col < 10) ? b4p[col] : 0.0f);
    }
    asm volatile("s_waitcnt lgkmcnt(0)" ::: "memory");
    if (lane < 8) {
      float p1[10], p2[10];
      #pragma unroll
      for (int j = 0; j < 10; ++j) {
        p1[j] = sp[(2 * lane) * 16 + j];
        p2[j] = sp[(2 * lane + 1) * 16 + j];
      }
      cpx v[4], w[4];
      build_state(p1, v);
      build_state(p2, w);
      float ir = 0.f, ii = 0.f;
      #pragma unroll
      for (int k = 0; k < 4; ++k) {
        ir += w[k].r*v[k].r + w[k].i*v[k].i;
        ii += w[k].r*v[k].i - w[k].i*v[k].r;
      }
      out[(size_t)blockIdx.x * 64 + wid * 8 + lane] = ir*ir + ii*ii;
    }
  }
}

extern "C" void kernel_launch(void* const* d_in, const int* in_sizes, int n_in,
                              void* d_out, int out_size, void* d_ws, size_t ws_size,
                              hipStream_t stream)
{
  const float* X  = (const float*)d_in[0];
  const float* W1 = (const float*)d_in[1];
  const float* b1 = (const float*)d_in[2];
  const float* W2 = (const float*)d_in[3];
  const float* b2 = (const float*)d_in[4];
  const float* W3 = (const float*)d_in[5];
  const float* b3 = (const float*)d_in[6];
  const float* W4 = (const float*)d_in[7];
  const float* b4 = (const float*)d_in[8];
  u16* wf = (u16*)d_ws;   // 207 blocks * 2048 B = 423936 B scratch

  prep_kernel<<<dim3(NBLOCKS), dim3(64), 0, stream>>>(W1, W2, W3, W4, wf);
  fused_kernel<<<dim3(1024), dim3(512), 0, stream>>>(X, b1, b2, b3, b4, wf,
                                                     (float*)d_out);
}

// Round 6
// 370.416 us; speedup vs baseline: 1.0002x; 1.0002x over previous
//
#include <hip/hip_runtime.h>
#include <hip/hip_bf16.h>
#include <stdint.h>

typedef unsigned short u16;
typedef unsigned int   u32;
typedef unsigned long long u64;
typedef __bf16 bf16x8 __attribute__((ext_vector_type(8)));
typedef float  f32x4  __attribute__((ext_vector_type(4)));

__device__ __forceinline__ u16 b2u(__bf16 b){ union U{__bf16 b; u16 u;} v; v.b=b; return v.u; }

__device__ __forceinline__ f32x4 MFMA16(bf16x8 a, bf16x8 b, f32x4 c) {
  return __builtin_amdgcn_mfma_f32_16x16x32_bf16(a, b, c, 0, 0, 0);
}

// ---- LDS: two 14336 B weight buffers + 8 x 2304 B wave-private scratch ----
#define LDS_WA   0
#define LDS_WB   14336
#define LDS_SCR  28672
#define SCR_STRIDE 2304
#define LDS_TOTAL 47104

// weight fragment blocks (2048 B each): layer bases in blocks
#define BL2 140   // L1: 10 kc x 14 nt = 140 blocks
#define BL3 189   // L2: 7 kc x 7 nt = 49
#define BL4 205   // L3: 4 kc x 4 nt = 16
#define NBLOCKS 207   // L4: 2 kc x 1 nt = 2

#define VMCNT0 asm volatile("s_waitcnt vmcnt(0)" ::: "memory")

// ---------------- weight prep: fp32 [N][K] -> bf16 hi/lo B-fragment blocks ----
// 16x16x32 B-frag: lane l holds col n = nt*16 + (l&15), k = kc*32 + (l>>4)*8 + j
// block = 2048 B = [hi: 64 lanes x 16 B][lo: 64 lanes x 16 B]
__global__ __launch_bounds__(64) void prep_kernel(
    const float* __restrict__ W1, const float* __restrict__ W2,
    const float* __restrict__ W3, const float* __restrict__ W4,
    u16* __restrict__ wf)
{
  int b = blockIdx.x, lane = threadIdx.x;
  const float* W; int NT, rel, Nv, Kv;
  if (b < BL2)      { W = W1; NT = 14; rel = b;       Nv = 200; Kv = 300; }
  else if (b < BL3) { W = W2; NT = 7;  rel = b - BL2; Nv = 100; Kv = 200; }
  else if (b < BL4) { W = W3; NT = 4;  rel = b - BL3; Nv = 50;  Kv = 100; }
  else              { W = W4; NT = 1;  rel = b - BL4; Nv = 10;  Kv = 50;  }
  int kc = rel / NT, nt = rel % NT;
  int n  = nt * 16 + (lane & 15);
  int kb = kc * 32 + ((lane >> 4) << 3);
  u16* dst = wf + (size_t)b * 1024;
  #pragma unroll
  for (int j = 0; j < 8; ++j) {
    int k = kb + j;
    float w = (n < Nv && k < Kv) ? W[n * Kv + k] : 0.0f;
    __bf16 h = (__bf16)w;
    __bf16 l = (__bf16)(w - (float)h);
    dst[lane * 8 + j]       = b2u(h);
    dst[512 + lane * 8 + j] = b2u(l);
  }
}

// ---- T14 reg staging (round-2/4-proven): issue loads early, LDS write late ----
template<int CHUNK>
__device__ __forceinline__ void stage_load(const char* __restrict__ g, float4* r, int tid) {
  constexpr int NS = (CHUNK + 8191) / 8192;
  #pragma unroll
  for (int it = 0; it < NS; ++it) {
    const int off = tid * 16 + it * 8192;
    if ((it + 1) * 8192 <= CHUNK) r[it] = *(const float4*)(g + off);
    else if (off < CHUNK)         r[it] = *(const float4*)(g + off);
  }
}
template<int CHUNK>
__device__ __forceinline__ void stage_write(char* lds, const float4* r, int tid) {
  constexpr int NS = (CHUNK + 8191) / 8192;
  #pragma unroll
  for (int it = 0; it < NS; ++it) {
    const int off = tid * 16 + it * 8192;
    if ((it + 1) * 8192 <= CHUNK) *(float4*)(lds + off) = r[it];
    else if (off < CHUNK)         *(float4*)(lds + off) = r[it];
  }
}

// ---- layer transition (wave-private, plain LDS, stride-72 rows) ----
// scratch: hi plane rows m=0..15 at byte m*72 (k_local*2 within row), lo at +1152
// writer: value(m = q*4+r, k_local = hh*16+col) ; reader: lane gets
// frag[j] = H[m=col][k = q*8+j] as two b64 at col*72 + q*16 (+8)
template<int TIN>
__device__ __forceinline__ void transition(const f32x4* acc,
    const float* __restrict__ bias, int nvalid,
    bf16x8* oh, bf16x8* ol, char* scr, int lane)
{
  const int col = lane & 15, q = lane >> 4;
  float bv[TIN];
  #pragma unroll
  for (int t = 0; t < TIN; ++t) {
    const int n = t * 16 + col;
    bv[t] = (n < nvalid) ? bias[n] : 0.0f;
  }
  constexpr int KC = (TIN + 1) / 2;
  #pragma unroll
  for (int kc = 0; kc < KC; ++kc) {
    #pragma unroll
    for (int hh = 0; hh < 2; ++hh) {
      const int t = 2 * kc + hh;
      #pragma unroll
      for (int r = 0; r < 4; ++r) {
        float v = 0.0f;
        if (t < TIN) v = fmaxf(acc[t][r] + bv[t], 0.0f);
        __bf16 h = (__bf16)v;
        __bf16 l = (__bf16)(v - (float)h);
        const int m = q * 4 + r;
        char* wp = scr + m * 72 + (hh * 16 + col) * 2;
        *(u16*)wp           = b2u(h);
        *(u16*)(wp + 1152)  = b2u(l);
      }
    }
    // wait for this wave's stores, and fence compiler reordering across phases
    asm volatile("s_waitcnt lgkmcnt(0)" ::: "memory");
    const char* rp = scr + col * 72 + q * 16;
    union { u64 u[2]; bf16x8 v; } ph, pl;
    ph.u[0] = *(const u64*)(rp);
    ph.u[1] = *(const u64*)(rp + 8);
    pl.u[0] = *(const u64*)(rp + 1152);
    pl.u[1] = *(const u64*)(rp + 1160);
    oh[kc] = ph.v;
    ol[kc] = pl.v;
  }
}

// ---- generic LDS-weight layer (A-fragments in registers) ----
template<int NT, int NKC>
__device__ __forceinline__ void layerN(char* lds, const char* wl,
    f32x4* acc, const bf16x8* ah, const bf16x8* al, int lane, int tid)
{
  constexpr int CH = NT * 2048;
  #pragma unroll
  for (int s = 0; s < NKC; ++s) {
    float4 sr[(CH + 8191) / 8192];
    if (s + 1 < NKC) stage_load<CH>(wl + (size_t)(s + 1) * CH, sr, tid);
    const char* wb = lds + ((s & 1) ? LDS_WB : LDS_WA);
    #pragma unroll
    for (int nt = 0; nt < NT; ++nt) {
      const char* bp = wb + nt * 2048 + (size_t)lane * 16;
      bf16x8 bh = *(const bf16x8*)bp;
      bf16x8 bl = *(const bf16x8*)(bp + 1024);
      acc[nt] = MFMA16(ah[s], bh, acc[nt]);
      acc[nt] = MFMA16(ah[s], bl, acc[nt]);
      acc[nt] = MFMA16(al[s], bh, acc[nt]);
    }
    if (s + 1 < NKC) { VMCNT0; stage_write<CH>(lds + ((s & 1) ? LDS_WA : LDS_WB), sr, tid); }
    __syncthreads();
  }
}

// ---- quantum epilogue (verified rounds 1-4) ----
struct cpx { float r, i; };
__device__ __forceinline__ void ry_pair(float c, float s, cpx& a, cpx& b) {
  cpx na = { c*a.r - s*b.r, c*a.i - s*b.i };
  cpx nb = { s*a.r + c*b.r, s*a.i + c*b.i };
  a = na; b = nb;
}
__device__ __forceinline__ void rx_pair(float c, float s, cpx& a, cpx& b) {
  cpx na = { c*a.r + s*b.i, c*a.i - s*b.r };
  cpx nb = { s*a.i + c*b.r, -s*a.r + c*b.i };
  a = na; b = nb;
}
__device__ void build_state(const float* p, cpx v[4]) {
  float a1 = 0.5f*p[1], a2 = 0.5f*p[2], a3 = 0.5f*p[3];
  float c2 = cosf(a2), s2 = sinf(a2), c3 = cosf(a3), s3 = sinf(a3);
  v[0] = { c2*c3, 0.f }; v[1] = { c2*s3, 0.f };
  v[2] = { s2*c3, 0.f }; v[3] = { s2*s3, 0.f };
  float c1 = cosf(a1), s1 = sinf(a1);
  rx_pair(c1, s1, v[0], v[1]); rx_pair(c1, s1, v[2], v[3]);
  rx_pair(c1, s1, v[0], v[2]); rx_pair(c1, s1, v[1], v[3]);
  float q1 = 0.5f*p[6], q2 = 0.5f*p[7], q3 = 0.5f*p[8], q4 = 0.5f*p[9];
  float c4 = cosf(q4), s4 = sinf(q4);
  rx_pair(c4, s4, v[1], v[3]);
  float cc = cosf(q3), ss = sinf(q3);
  ry_pair(cc, ss, v[0], v[1]); ry_pair(cc, ss, v[2], v[3]);
  cc = cosf(q2); ss = sinf(q2);
  ry_pair(cc, ss, v[0], v[2]); ry_pair(cc, ss, v[1], v[3]);
  cc = cosf(q1); ss = sinf(q1);
  rx_pair(cc, ss, v[0], v[1]); rx_pair(cc, ss, v[2], v[3]);
  rx_pair(cc, ss, v[0], v[2]); rx_pair(cc, ss, v[1], v[3]);
}

__device__ __forceinline__ bf16x8 cvt8(float4 a, float4 b) {
  bf16x8 r;
  r[0]=(__bf16)a.x; r[1]=(__bf16)a.y; r[2]=(__bf16)a.z; r[3]=(__bf16)a.w;
  r[4]=(__bf16)b.x; r[5]=(__bf16)b.y; r[6]=(__bf16)b.z; r[7]=(__bf16)b.w;
  return r;
}
__device__ __forceinline__ void loadX(const float* xp, int kc, int q,
                                      float4& a, float4& b) {
  int k0 = kc * 32 + q * 8;
  a = (k0     < 300) ? *(const float4*)(xp + k0)     : make_float4(0,0,0,0);
  b = (k0 + 4 < 300) ? *(const float4*)(xp + k0 + 4) : make_float4(0,0,0,0);
}

// ---- fused kernel: 8 waves x 16 rows = 128 rows of [2B,300] per WG ----
__global__ __launch_bounds__(512, 2) void fused_kernel(
    const float* __restrict__ X,
    const float* __restrict__ b1p, const float* __restrict__ b2p,
    const float* __restrict__ b3p, const float* __restrict__ b4p,
    const u16* __restrict__ wf,
    float* __restrict__ out)
{
  __shared__ char lds[LDS_TOTAL] __attribute__((aligned(16)));
  const int tid  = threadIdx.x;
  const int lane = tid & 63;
  const int wid  = tid >> 6;
  const int q    = lane >> 4;
  char* scr = lds + LDS_SCR + wid * SCR_STRIDE;
  const char* wfc = (const char*)wf;
  const long rowbase = (long)blockIdx.x * 128 + wid * 16;
  const float* xp = X + (rowbase + (lane & 15)) * 300;

  // prologue: stage L1 chunk0 (kc0, nts 0-6), load X kc0
  float4 s0[2];
  stage_load<14336>(wfc, s0, tid);
  float4 fxa, fxb;
  loadX(xp, 0, q, fxa, fxb);
  VMCNT0;
  stage_write<14336>(lds + LDS_WA, s0, tid);
  bf16x8 xcur = cvt8(fxa, fxb);
  __syncthreads();

  // ---- L1: 20 half-steps (10 kc x 2 nt-halves); 7 nt x 2 MFMA per step ----
  f32x4 acc1[14] = {};
  #pragma unroll
  for (int s = 0; s < 20; ++s) {
    float4 sr[2];
    if (s < 19) stage_load<14336>(wfc + (size_t)(s + 1) * 14336, sr, tid);
    if (!(s & 1) && s < 18) loadX(xp, (s >> 1) + 1, q, fxa, fxb);
    const char* wb = lds + ((s & 1) ? LDS_WB : LDS_WA);
    f32x4* acch = acc1 + (s & 1) * 7;
    #pragma unroll
    for (int nt = 0; nt < 7; ++nt) {
      const char* bp = wb + nt * 2048 + (size_t)lane * 16;
      bf16x8 bh = *(const bf16x8*)bp;
      bf16x8 bl = *(const bf16x8*)(bp + 1024);
      acch[nt] = MFMA16(xcur, bh, acch[nt]);
      acch[nt] = MFMA16(xcur, bl, acch[nt]);
    }
    if (s < 19) { VMCNT0; stage_write<14336>(lds + ((s & 1) ? LDS_WA : LDS_WB), sr, tid); }
    if ((s & 1) && s < 19) xcur = cvt8(fxa, fxb);
    __syncthreads();
  }

  // ---- L1 -> L2 ----
  float4 s2[2];
  stage_load<14336>(wfc + (size_t)BL2 * 2048, s2, tid);
  bf16x8 h1h[7], h1l[7];
  transition<14>(acc1, b1p, 200, h1h, h1l, scr, lane);
  VMCNT0;
  stage_write<14336>(lds + LDS_WA, s2, tid);
  __syncthreads();

  f32x4 acc2[7] = {};
  layerN<7, 7>(lds, wfc + (size_t)BL2 * 2048, acc2, h1h, h1l, lane, tid);

  // ---- L2 -> L3 ----
  float4 s3[1];
  stage_load<8192>(wfc + (size_t)BL3 * 2048, s3, tid);
  bf16x8 h2h[4], h2l[4];
  transition<7>(acc2, b2p, 100, h2h, h2l, scr, lane);
  VMCNT0;
  stage_write<8192>(lds + LDS_WA, s3, tid);
  __syncthreads();

  f32x4 acc3[4] = {};
  layerN<4, 4>(lds, wfc + (size_t)BL3 * 2048, acc3, h2h, h2l, lane, tid);

  // ---- L3 -> L4 ----
  float4 s4[1];
  stage_load<2048>(wfc + (size_t)BL4 * 2048, s4, tid);
  bf16x8 h3h[2], h3l[2];
  transition<4>(acc3, b3p, 50, h3h, h3l, scr, lane);
  VMCNT0;
  stage_write<2048>(lds + LDS_WA, s4, tid);
  __syncthreads();

  f32x4 acc4[1] = {};
  layerN<1, 2>(lds, wfc + (size_t)BL4 * 2048, acc4, h3h, h3l, lane, tid);

  // ---- epilogue: params via wave-private f32 scratch, quantum math, store ----
  {
    const int col = lane & 15;
    float* sp = (float*)scr;   // [16 rows][16 cols] f32
    #pragma unroll
    for (int r = 0; r < 4; ++r) {
      const int row = q * 4 + r;
      sp[row * 16 + col] = acc4[0][r] + ((col < 10) ? b4p[col] : 0.0f);
    }
    asm volatile("s_waitcnt lgkmcnt(0)" ::: "memory");
    if (lane < 8) {
      float p1[10], p2[10];
      #pragma unroll
      for (int j = 0; j < 10; ++j) {
        p1[j] = sp[(2 * lane) * 16 + j];
        p2[j] = sp[(2 * lane + 1) * 16 + j];
      }
      cpx v[4], w[4];
      build_state(p1, v);
      build_state(p2, w);
      float ir = 0.f, ii = 0.f;
      #pragma unroll
      for (int k = 0; k < 4; ++k) {
        ir += w[k].r*v[k].r + w[k].i*v[k].i;
        ii += w[k].r*v[k].i - w[k].i*v[k].r;
      }
      out[(size_t)blockIdx.x * 64 + wid * 8 + lane] = ir*ir + ii*ii;
    }
  }
}

extern "C" void kernel_launch(void* const* d_in, const int* in_sizes, int n_in,
                              void* d_out, int out_size, void* d_ws, size_t ws_size,
                              hipStream_t stream)
{
  const float* X  = (const float*)d_in[0];
  const float* W1 = (const float*)d_in[1];
  const float* b1 = (const float*)d_in[2];
  const float* W2 = (const float*)d_in[3];
  const float* b2 = (const float*)d_in[4];
  const float* W3 = (const float*)d_in[5];
  const float* b3 = (const float*)d_in[6];
  const float* W4 = (const float*)d_in[7];
  const float* b4 = (const float*)d_in[8];
  u16* wf = (u16*)d_ws;   // 207 blocks * 2048 B = 423936 B scratch

  prep_kernel<<<dim3(NBLOCKS), dim3(64), 0, stream>>>(W1, W2, W3, W4, wf);
  fused_kernel<<<dim3(1024), dim3(512), 0, stream>>>(X, b1, b2, b3, b4, wf,
                                                     (float*)d_out);
}